// Round 10
// baseline (283.321 us; speedup 1.0000x reference)
//
#include <hip/hip_runtime.h>
#include <math.h>

#define NGRAPHS 8
#define KBSHIFT 8            // bucket = dst >> 8  (256 nodes per bucket)
#define BSZ 256              // nodes per bucket
#define KMAX 512             // >= K = ceil(N/BSZ) = 391
#define PCHUNK 3125          // edges per partition block (stage fits LDS)
#define HIST_BLOCKS 256      // histogram blocks inside the fused gemm1 launch
// NOTE: partition packs (dst&255)<<23 | src -> requires src < 2^23 (N=100k ok)

typedef _Float16 h2 __attribute__((ext_vector_type(2)));

__device__ __forceinline__ h2 as_h2(unsigned u) { return __builtin_bit_cast(h2, u); }
__device__ __forceinline__ unsigned as_u(h2 h) { return __builtin_bit_cast(unsigned, h); }
__device__ __forceinline__ unsigned pkf16(float a, float b) {
    auto v = __builtin_amdgcn_cvt_pkrtz(a, b);   // v_cvt_pkrtz_f16_f32
    return __builtin_bit_cast(unsigned, v);
}
// fast tanh: 1 - 2/(e^{2x}+1); exact at +-inf ends, ~1e-6 rel err
__device__ __forceinline__ float ftanh(float x) {
    float t = __expf(2.0f * x);
    return 1.0f - 2.0f * __builtin_amdgcn_rcpf(t + 1.0f);
}

// ---------------------------------------------------------------------------
// FUSED: blocks [0,HIST_BLOCKS) build the dst bucket histogram; the LAST
// hist block to finish (device done-counter at bcnt[KMAX]) scans it into
// bbase/bcursor and computes w3s. Blocks [HIST_BLOCKS,...) do GEMM-1
// (fp32 in -> fp16 out). Hist and GEMM are independent; stream order vs
// partition_kernel guarantees the scan is complete before it's consumed.
// ---------------------------------------------------------------------------
__global__ __launch_bounds__(256) void gemm1_hist_kernel(
    const float* __restrict__ in, const float* __restrict__ W,
    const float* __restrict__ bias, unsigned* __restrict__ out,
    const int* __restrict__ dst, int* __restrict__ bcnt,
    int* __restrict__ bbase, int* __restrict__ bcursor,
    int* __restrict__ rowptr, const float* __restrict__ W3,
    const float* __restrict__ b3, float* __restrict__ w3s,
    int E, int K, int N)
{
    const int t = threadIdx.x;
    if (blockIdx.x < HIST_BLOCKS) {
        __shared__ int h[KMAX];
        __shared__ int pre[256];
        __shared__ int lastflag;
        h[t] = 0; h[t + 256] = 0;
        __syncthreads();
        for (int e = blockIdx.x * 256 + t; e < E; e += HIST_BLOCKS * 256)
            atomicAdd(&h[dst[e] >> KBSHIFT], 1);
        __syncthreads();
        for (int k = t; k < K; k += 256)
            if (h[k] > 0) atomicAdd(&bcnt[k], h[k]);
        // __syncthreads drains vmcnt; then publish completion.
        __syncthreads();
        if (t == 0) {
            __threadfence();
            int old = atomicAdd(&bcnt[KMAX], 1);   // done counter
            lastflag = (old == HIST_BLOCKS - 1) ? 1 : 0;
        }
        __syncthreads();
        if (!lastflag) return;
        // ---- last block: scan 512 bucket counts (2 per thread) ----
        __threadfence();
        int c0 = __hip_atomic_load(&bcnt[2 * t],     __ATOMIC_RELAXED, __HIP_MEMORY_SCOPE_AGENT);
        int c1 = __hip_atomic_load(&bcnt[2 * t + 1], __ATOMIC_RELAXED, __HIP_MEMORY_SCOPE_AGENT);
        int pair = c0 + c1;
        pre[t] = pair;
        __syncthreads();
        int x = pair;
        #pragma unroll
        for (int off = 1; off < 256; off <<= 1) {
            int u = (t >= off) ? pre[t - off] : 0;
            __syncthreads();
            x += u;
            pre[t] = x;
            __syncthreads();
        }
        int ebase = x - pair;                     // exclusive prefix of entry 2t
        bbase[2 * t] = ebase;      bcursor[2 * t] = ebase;
        bbase[2 * t + 1] = ebase + c0; bcursor[2 * t + 1] = ebase + c0;
        if (t == 0) rowptr[N] = E;                // bbase[K] covered by scan (=E)
        if (t < 64) {
            float s = 0.f;
            for (int o = 0; o < 64; ++o) s += W3[o * 64 + t];
            w3s[t] = s;
        }
        if (t == 64) {
            float bs = 0.f;
            for (int k = 0; k < 64; ++k) bs += b3[k];
            w3s[64] = bs;
        }
        return;
    }
    // ---- GEMM-1 ----
    __shared__ float Wt[64 * 68];   // Wt[i*68 + o] = W[o][i]
    __shared__ float xs[16 * 65];
    const int node0 = (blockIdx.x - HIST_BLOCKS) * 16;
    #pragma unroll
    for (int k = 0; k < 16; ++k) {
        int idx = k * 256 + t;
        int o = idx >> 6, i = idx & 63;
        Wt[i * 68 + o] = W[idx];
    }
    #pragma unroll
    for (int k = 0; k < 4; ++k) {
        int idx = k * 256 + t;
        int nl = idx >> 6, i = idx & 63;
        xs[nl * 65 + i] = in[node0 * 64 + idx];
    }
    __syncthreads();
    const int nl = t >> 4;
    const int o4 = t & 15;
    float4 acc = make_float4(0.f, 0.f, 0.f, 0.f);
    #pragma unroll
    for (int i = 0; i < 64; ++i) {
        float xv = xs[nl * 65 + i];
        float4 wv = *(const float4*)&Wt[i * 68 + o4 * 4];
        acc.x += xv * wv.x;
        acc.y += xv * wv.y;
        acc.z += xv * wv.z;
        acc.w += xv * wv.w;
    }
    float4 b4 = ((const float4*)bias)[o4];
    acc.x += b4.x; acc.y += b4.y; acc.z += b4.z; acc.w += b4.w;
    uint2 o;
    o.x = pkf16(acc.x, acc.y);
    o.y = pkf16(acc.z, acc.w);
    ((uint2*)out)[(node0 + nl) * 16 + o4] = o;
}

// ---------------------------------------------------------------------------
// GEMM-2: out[n][o] = sum_i ftanh(in[n][i]) * W[o][i] + b[o]  (fp16 in/out)
// ---------------------------------------------------------------------------
__global__ __launch_bounds__(256) void gemm2_kernel(
    const unsigned* __restrict__ in, const float* __restrict__ W,
    const float* __restrict__ bias, unsigned* __restrict__ out)
{
    __shared__ float Wt[64 * 68];
    __shared__ float xs[16 * 65];
    const int t = threadIdx.x;
    const int node0 = blockIdx.x * 16;
    #pragma unroll
    for (int k = 0; k < 16; ++k) {
        int idx = k * 256 + t;
        int o = idx >> 6, i = idx & 63;
        Wt[i * 68 + o] = W[idx];
    }
    #pragma unroll
    for (int k = 0; k < 2; ++k) {
        int idx = k * 256 + t;
        int nl = idx >> 5, ii = (idx & 31) * 2;
        h2 hv = as_h2(in[node0 * 32 + idx]);
        xs[nl * 65 + ii]     = ftanh((float)hv.x);
        xs[nl * 65 + ii + 1] = ftanh((float)hv.y);
    }
    __syncthreads();
    const int nl = t >> 4;
    const int o4 = t & 15;
    float4 acc = make_float4(0.f, 0.f, 0.f, 0.f);
    #pragma unroll
    for (int i = 0; i < 64; ++i) {
        float xv = xs[nl * 65 + i];
        float4 wv = *(const float4*)&Wt[i * 68 + o4 * 4];
        acc.x += xv * wv.x;
        acc.y += xv * wv.y;
        acc.z += xv * wv.z;
        acc.w += xv * wv.w;
    }
    float4 b4 = ((const float4*)bias)[o4];
    acc.x += b4.x; acc.y += b4.y; acc.z += b4.z; acc.w += b4.w;
    uint2 o;
    o.x = pkf16(acc.x, acc.y);
    o.y = pkf16(acc.z, acc.w);
    ((uint2*)out)[(node0 + nl) * 16 + o4] = o;
}

// ---------------------------------------------------------------------------
// Partition edges into buckets with LDS-staged, bucket-ordered output
// (coalesced per-bucket runs instead of 4B scatters).
// ---------------------------------------------------------------------------
__global__ __launch_bounds__(512) void partition_kernel(
    const int* __restrict__ src, const int* __restrict__ dst,
    int* __restrict__ bcursor, unsigned* __restrict__ pairs, int E, int K)
{
    __shared__ int h[512];
    __shared__ int sh[512];
    __shared__ int base[512];
    __shared__ int cur[512];
    __shared__ unsigned val[PCHUNK + 3];
    __shared__ unsigned short bk[PCHUNK + 3];
    const int t = threadIdx.x;
    const int lo = blockIdx.x * PCHUNK;
    int hi = lo + PCHUNK; if (hi > E) hi = E;
    const int cnt = hi - lo;

    h[t] = 0; cur[t] = 0;
    __syncthreads();
    for (int e = lo + t; e < hi; e += 512)
        atomicAdd(&h[dst[e] >> KBSHIFT], 1);
    __syncthreads();
    int v = h[t];
    int x = v;
    #pragma unroll
    for (int off = 1; off < 512; off <<= 1) {
        int u = (t >= off) ? h[t - off] : 0;
        __syncthreads();
        x += u;
        h[t] = x;
        __syncthreads();
    }
    sh[t] = x - v;
    base[t] = (t < K && v > 0) ? atomicAdd(&bcursor[t], v) : 0;
    __syncthreads();
    for (int e = lo + t; e < hi; e += 512) {
        int d = dst[e];
        int k = d >> KBSHIFT;
        int pos = atomicAdd(&cur[k], 1);
        int j = sh[k] + pos;
        val[j] = ((unsigned)(d & (BSZ - 1)) << 23) | (unsigned)src[e];
        bk[j] = (unsigned short)k;
    }
    __syncthreads();
    for (int j = t; j < cnt; j += 512) {
        int k = bk[j];
        pairs[base[k] + (j - sh[k])] = val[j];
    }
}

// ---------------------------------------------------------------------------
// Per-bucket CSR finalize: LDS hist -> scan -> rowptr + esrc scatter into
// the bucket's contiguous window.
// ---------------------------------------------------------------------------
__global__ __launch_bounds__(256) void bucket_build_kernel(
    const unsigned* __restrict__ pairs, const int* __restrict__ bbase,
    int* __restrict__ rowptr, int* __restrict__ esrc, int N)
{
    __shared__ int cnt[BSZ];
    __shared__ int tmp[BSZ];
    __shared__ int cur[BSZ];
    int k = blockIdx.x;
    int t = threadIdx.x;
    int ebase = bbase[k], eend = bbase[k + 1];

    cnt[t] = 0;
    __syncthreads();
    for (int e = ebase + t; e < eend; e += BSZ)
        atomicAdd(&cnt[pairs[e] >> 23], 1);
    __syncthreads();

    int v = cnt[t];
    tmp[t] = v;
    __syncthreads();
    #pragma unroll
    for (int off = 1; off < BSZ; off <<= 1) {
        int u = (t >= off) ? tmp[t - off] : 0;
        __syncthreads();
        tmp[t] += u;
        __syncthreads();
    }
    int excl = tmp[t] - v;
    cur[t] = excl;
    int n = (k << KBSHIFT) + t;
    if (n < N) rowptr[n] = ebase + excl;
    __syncthreads();

    for (int e = ebase + t; e < eend; e += BSZ) {
        unsigned p = pairs[e];
        int pos = atomicAdd(&cur[p >> 23], 1);
        esrc[ebase + pos] = (int)(p & 0x7fffffu);
    }
}

// ---------------------------------------------------------------------------
// Gather-aggregate, packed fp16 accumulation (v_pk_add_f16), 2 nodes/wave.
// ---------------------------------------------------------------------------
__global__ __launch_bounds__(256) void gather_agg_kernel(
    const uint4* __restrict__ m, const int* __restrict__ esrc,
    const int* __restrict__ rowptr, uint4* __restrict__ out, int N)
{
    const int t = threadIdx.x;
    const int n = blockIdx.x * 8 + (t >> 5);
    const int l32 = t & 31;
    const int sub = l32 >> 3, c = l32 & 7;
    h2 a0 = {0, 0}, a1 = {0, 0}, a2 = {0, 0}, a3 = {0, 0};
    if (n < N) {
        int beg = rowptr[n], end = rowptr[n + 1];
        int e = beg + sub;
        for (; e + 4 < end; e += 8) {
            int sA = esrc[e], sB = esrc[e + 4];
            uint4 vA = m[(size_t)sA * 8 + c];
            uint4 vB = m[(size_t)sB * 8 + c];
            a0 += as_h2(vA.x); a1 += as_h2(vA.y);
            a2 += as_h2(vA.z); a3 += as_h2(vA.w);
            a0 += as_h2(vB.x); a1 += as_h2(vB.y);
            a2 += as_h2(vB.z); a3 += as_h2(vB.w);
        }
        if (e < end) {
            uint4 vA = m[(size_t)esrc[e] * 8 + c];
            a0 += as_h2(vA.x); a1 += as_h2(vA.y);
            a2 += as_h2(vA.z); a3 += as_h2(vA.w);
        }
    }
    #pragma unroll
    for (int d = 8; d <= 16; d <<= 1) {
        a0 += as_h2(__shfl_xor(as_u(a0), d));
        a1 += as_h2(__shfl_xor(as_u(a1), d));
        a2 += as_h2(__shfl_xor(as_u(a2), d));
        a3 += as_h2(__shfl_xor(as_u(a3), d));
    }
    if (sub == 0 && n < N)
        out[(size_t)n * 8 + c] = make_uint4(as_u(a0), as_u(a1), as_u(a2), as_u(a3));
}

// ---------------------------------------------------------------------------
// Gather + collapsed layer 3, packed fp16 loop + fp32 tanh/w3s epilogue.
// Also zeroes d_out.
// ---------------------------------------------------------------------------
__global__ __launch_bounds__(256) void gather_s3_kernel(
    const uint4* __restrict__ m, const int* __restrict__ esrc,
    const int* __restrict__ rowptr, const float* __restrict__ w3s,
    float* __restrict__ s3, float* __restrict__ outz, int N)
{
    const int t = threadIdx.x;
    if (blockIdx.x == 0 && t < NGRAPHS) outz[t] = 0.f;
    const int n = blockIdx.x * 8 + (t >> 5);
    const int l32 = t & 31;
    const int sub = l32 >> 3, c = l32 & 7;
    h2 a0 = {0, 0}, a1 = {0, 0}, a2 = {0, 0}, a3 = {0, 0};
    if (n < N) {
        int beg = rowptr[n], end = rowptr[n + 1];
        int e = beg + sub;
        for (; e + 4 < end; e += 8) {
            int sA = esrc[e], sB = esrc[e + 4];
            uint4 vA = m[(size_t)sA * 8 + c];
            uint4 vB = m[(size_t)sB * 8 + c];
            a0 += as_h2(vA.x); a1 += as_h2(vA.y);
            a2 += as_h2(vA.z); a3 += as_h2(vA.w);
            a0 += as_h2(vB.x); a1 += as_h2(vB.y);
            a2 += as_h2(vB.z); a3 += as_h2(vB.w);
        }
        if (e < end) {
            uint4 vA = m[(size_t)esrc[e] * 8 + c];
            a0 += as_h2(vA.x); a1 += as_h2(vA.y);
            a2 += as_h2(vA.z); a3 += as_h2(vA.w);
        }
    }
    #pragma unroll
    for (int d = 8; d <= 16; d <<= 1) {
        a0 += as_h2(__shfl_xor(as_u(a0), d));
        a1 += as_h2(__shfl_xor(as_u(a1), d));
        a2 += as_h2(__shfl_xor(as_u(a2), d));
        a3 += as_h2(__shfl_xor(as_u(a3), d));
    }
    float4 w0 = ((const float4*)w3s)[c * 2];
    float4 w1 = ((const float4*)w3s)[c * 2 + 1];
    float partial = ftanh((float)a0.x) * w0.x + ftanh((float)a0.y) * w0.y
                  + ftanh((float)a1.x) * w0.z + ftanh((float)a1.y) * w0.w
                  + ftanh((float)a2.x) * w1.x + ftanh((float)a2.y) * w1.y
                  + ftanh((float)a3.x) * w1.z + ftanh((float)a3.y) * w1.w;
    partial += __shfl_xor(partial, 1);
    partial += __shfl_xor(partial, 2);
    partial += __shfl_xor(partial, 4);
    if (l32 == 0 && n < N) s3[n] = partial + w3s[64];
}

// ---------------------------------------------------------------------------
// per_graph[n2g[n]] += sum_{e in in(n)} s3[esrc[e]]. n2g is SORTED, so most
// waves are graph-uniform: ballot-check -> xor-shuffle reduce -> one atomic
// per wave. Boundary/tail waves fall back to per-lane atomics.
// ---------------------------------------------------------------------------
__global__ __launch_bounds__(256) void graph_reduce_kernel(
    const float* __restrict__ s3, const int* __restrict__ esrc,
    const int* __restrict__ rowptr, const int* __restrict__ n2g,
    float* __restrict__ out, int N)
{
    const int t = threadIdx.x;
    const int n = blockIdx.x * 256 + t;
    const bool valid = n < N;
    float acc = 0.f;
    int g = -1;
    if (valid) {
        g = n2g[n];
        for (int e = rowptr[n]; e < rowptr[n + 1]; ++e) acc += s3[esrc[e]];
    }
    int g0 = __shfl(g, 0);
    bool uni = __ballot(valid && (g == g0)) == 0xFFFFFFFFFFFFFFFFull;
    if (uni) {
        #pragma unroll
        for (int d = 1; d <= 32; d <<= 1) acc += __shfl_xor(acc, d);
        if ((t & 63) == 0) unsafeAtomicAdd(&out[g0], acc);
    } else if (valid) {
        unsafeAtomicAdd(&out[g], acc);
    }
}

// ---------------------------------------------------------------------------
extern "C" void kernel_launch(void* const* d_in, const int* in_sizes, int n_in,
                              void* d_out, int out_size, void* d_ws, size_t ws_size,
                              hipStream_t stream)
{
    const float* x   = (const float*)d_in[0];
    const float* W1  = (const float*)d_in[1];
    const float* b1  = (const float*)d_in[2];
    const float* W2  = (const float*)d_in[3];
    const float* b2  = (const float*)d_in[4];
    const float* W3  = (const float*)d_in[5];
    const float* b3  = (const float*)d_in[6];
    const int*   src = (const int*)d_in[7];
    const int*   dst = (const int*)d_in[8];
    const int*   n2g = (const int*)d_in[9];

    const int N = in_sizes[0] / 64;   // 100000
    const int E = in_sizes[7];        // 1600000
    const int K = (N + BSZ - 1) >> KBSHIFT;   // 391 buckets
    const int nb = (N + 255) / 256;

    // ---- workspace carve-up (256B-aligned) ----
    char* p = (char*)d_ws;
    auto carve = [&](size_t bytes) {
        char* r = p;
        p += (bytes + 255) & ~(size_t)255;
        return r;
    };
    unsigned* A     = (unsigned*)carve((size_t)N * 64 * 2);  // m1, later m2
    unsigned* B     = (unsigned*)carve((size_t)N * 64 * 2);  // pairs, later agg1
    float* s3b      = (float*)carve((size_t)N * sizeof(float));
    float* w3s      = (float*)carve(65 * sizeof(float));
    int*   bcnt     = (int*)carve((KMAX + 1) * sizeof(int)); // [KMAX] = done ctr
    int*   bbase    = (int*)carve((KMAX + 1) * sizeof(int));
    int*   bcursor  = (int*)carve(KMAX * sizeof(int));
    int*   rowptr   = (int*)carve((size_t)(N + 1) * sizeof(int));
    int*   esrc     = (int*)carve((size_t)E * sizeof(int));
    unsigned* pairs = (unsigned*)B;   // dead before gather_agg writes B
    float* out      = (float*)d_out;

    const int gemm_blocks = N / 16;                      // 6250
    const int gath_blocks = (N + 7) / 8;                 // 2 nodes/wave
    const int part_blocks = (E + PCHUNK - 1) / PCHUNK;   // 512

    // ---- bcnt + done counter zero ----
    (void)hipMemsetAsync(bcnt, 0, (KMAX + 1) * sizeof(int), stream);

    // ---- fused: dst histogram (+last-block scan +w3s) & GEMM-1 ----
    gemm1_hist_kernel<<<HIST_BLOCKS + gemm_blocks, 256, 0, stream>>>(
        x, W1, b1, A, dst, bcnt, bbase, bcursor, rowptr, W3, b3, w3s, E, K, N);

    // ---- CSR build ----
    partition_kernel<<<part_blocks, 512, 0, stream>>>(src, dst, bcursor, pairs, E, K);
    bucket_build_kernel<<<K, BSZ, 0, stream>>>(pairs, bbase, rowptr, esrc, N);

    // ---- gather-1 (packed fp16): A (m1) -> B (agg1) ----
    gather_agg_kernel<<<gath_blocks, 256, 0, stream>>>(
        (const uint4*)A, esrc, rowptr, (uint4*)B, N);

    // ---- GEMM-2 (ftanh fused on input): B (agg1) -> A (m2) ----
    gemm2_kernel<<<gemm_blocks, 256, 0, stream>>>(B, W2, b2, A);

    // ---- Layer 3 collapsed + fused into gather-2 (also zeroes d_out) ----
    gather_s3_kernel<<<gath_blocks, 256, 0, stream>>>(
        (const uint4*)A, esrc, rowptr, w3s, s3b, out, N);

    graph_reduce_kernel<<<nb, 256, 0, stream>>>(s3b, esrc, rowptr, n2g, out, N);
}